// Round 1
// baseline (7815.871 us; speedup 1.0000x reference)
//
#include <hip/hip_runtime.h>
#include <hip/hip_bf16.h>
#include <stdint.h>

typedef __attribute__((ext_vector_type(8))) short short8;   // 8 bf16 (4 VGPRs) MFMA frag
typedef __attribute__((ext_vector_type(4))) float f32x4;    // MFMA acc
typedef unsigned long long u64;
typedef unsigned int u32;

// ---------- helpers ----------
__device__ __forceinline__ float bf2f(unsigned short s){
  union { float f; u32 u; } v; v.u = ((u32)s) << 16; return v.f;
}
__device__ __forceinline__ unsigned short f2bf(float f){
  u32 u = __float_as_uint(f);
  u32 r = (u + 0x7fffu + ((u >> 16) & 1u)) >> 16;   // RNE
  return (unsigned short)r;
}
__device__ __forceinline__ float sigm(float x){ return 1.0f / (1.0f + __expf(-x)); }
__device__ __forceinline__ float tanh_(float x){ return 1.0f - 2.0f/(__expf(2.0f*x) + 1.0f); }
__device__ __forceinline__ u64 pack4(float a, float b, float c, float d){
  return (u64)f2bf(a) | ((u64)f2bf(b)<<16) | ((u64)f2bf(c)<<32) | ((u64)f2bf(d)<<48);
}

// =====================================================================
// K0a: pack weights into MFMA fragment layout (bf16)
//  frag convention (16x16x32): lane l elem j -> [nonK = l&15][k = (l>>4)*8 + j]
// pack1: w_hh1 (768x256)  wave w owns hidden block 32w; tiles m: 0,1=r 2,3=z 4,5=n
// pack2: [w_ih2f; w_ih2b] as 768 G-rows x 256
// pack3: per-dir w_hh2 (384x128), wave w owns hidden block 16w, tiles m=r,z,n
// =====================================================================
__global__ void k_pack(const float* __restrict__ w_hh1,
                       const float* __restrict__ w_ih2f, const float* __restrict__ w_ih2b,
                       const float* __restrict__ w_hh2f, const float* __restrict__ w_hh2b,
                       unsigned short* __restrict__ pack1,
                       unsigned short* __restrict__ pack2,
                       unsigned short* __restrict__ pack3)
{
  int tid = blockIdx.x*256 + threadIdx.x;
  const float* src;
  unsigned short* dst;
  long idx;
  if (tid < 24576){
    int f = tid>>6, l = tid&63;
    int w = f/48, rem = f%48, m = rem>>3, kt = rem&7;
    int g  = ((m>>1)<<8) + (w<<5) + ((m&1)<<4) + (l&15);
    int kb = (kt<<5) + ((l>>4)<<3);
    src = w_hh1 + (size_t)g*256 + kb;
    dst = pack1; idx = tid;
  } else if (tid < 49152){
    int t2 = tid - 24576;
    int f = t2>>6, l = t2&63;
    int w = f/48, rem = f%48, m = rem>>3, kt = rem&7;
    int G  = 96*w + (m<<4) + (l&15);
    int kb = (kt<<5) + ((l>>4)<<3);
    const float* W = (G < 384) ? w_ih2f : w_ih2b;
    src = W + (size_t)(G % 384)*256 + kb;
    dst = pack2; idx = t2;
  } else {
    int t3 = tid - 49152;
    int f = t3>>6, l = t3&63;
    int dir = f/96, r96 = f%96, w = r96/12, r12 = r96%12, m = r12>>2, kt = r12&3;
    int Grow = (m<<7) + (w<<4) + (l&15);
    int kb = (kt<<5) + ((l>>4)<<3);
    src = (dir ? w_hh2b : w_hh2f) + (size_t)Grow*128 + kb;
    dst = pack3; idx = t3;
  }
  u64 lo = (u64)f2bf(src[0]) | ((u64)f2bf(src[1])<<16) | ((u64)f2bf(src[2])<<32) | ((u64)f2bf(src[3])<<48);
  u64 hi = (u64)f2bf(src[4]) | ((u64)f2bf(src[5])<<16) | ((u64)f2bf(src[6])<<32) | ((u64)f2bf(src[7])<<48);
  *(u64*)(dst + (size_t)idx*8)     = lo;
  *(u64*)(dst + (size_t)idx*8 + 4) = hi;
}

// =====================================================================
// K0b: xgV[v][g] = emb[v,:]·w_ih1[g,:] + b_ih1[g] + (g<512 ? b_hh1[g] : 0)
// bf16 output, 128x768. (b_hh for r,z folded in; b_hh_n stays separate.)
// =====================================================================
__global__ void k_xgv(const float* __restrict__ emb, const float* __restrict__ w_ih1,
                      const float* __restrict__ b_ih1, const float* __restrict__ b_hh1,
                      unsigned short* __restrict__ xgV)
{
  int tid = blockIdx.x*256 + threadIdx.x;        // 98304 total
  int v = tid / 768, g = tid % 768;
  float s = b_ih1[g] + (g < 512 ? b_hh1[g] : 0.0f);
  const f32x4* e4 = (const f32x4*)(emb   + (size_t)v*312);
  const f32x4* w4 = (const f32x4*)(w_ih1 + (size_t)g*312);
  #pragma unroll 4
  for (int i=0;i<78;i++){
    f32x4 a = e4[i], b = w4[i];
    s += a[0]*b[0] + a[1]*b[1] + a[2]*b[2] + a[3]*b[3];
  }
  xgV[tid] = f2bf(s);
}

// =====================================================================
// K1: layer-1 scan. 8 wgs x 512 thr (8 waves). wg p owns batch [16p,16p+16).
// Wave w owns hidden block u0=32w (gates u0.., 256+u0.., 512+u0..).
// Weights stationary in 192 VGPRs/lane. h fp32 in regs (owner lane) +
// bf16 copy in swizzled LDS for MFMA B-frags. LN fused; writes hn bf16.
// D = mfma(Wfrag, hfrag): row=gate (lane>>4)*4+reg, col=batch lane&15.
// =====================================================================
__launch_bounds__(512, 2)
__global__ void k_scan1(const int* __restrict__ token,
                        const unsigned short* __restrict__ xgV,
                        const unsigned short* __restrict__ pack1,
                        const float* __restrict__ b_hh1,
                        const float* __restrict__ ln_g, const float* __restrict__ ln_b,
                        unsigned short* __restrict__ hn)
{
  __shared__ __align__(16) char hb[2][8192];     // [16 batch][256] bf16, XOR-swizzled
  __shared__ __align__(16) char xgb[2][24576];   // [16 batch][768] bf16, XOR-swizzled
  __shared__ __align__(16) float lngb[512];      // ln_g | ln_b
  __shared__ __align__(8)  float scr[2][16][8][2];

  const int tid = threadIdx.x;
  const int w = tid>>6, lane = tid&63, hi = lane>>4, col = lane&15;
  const int b0 = blockIdx.x * 16;

  // persistent weight fragments: 6 Mtiles x 8 Ktiles
  short8 wf[6][8];
  #pragma unroll
  for (int m=0;m<6;m++)
    #pragma unroll
    for (int kt=0;kt<8;kt++)
      wf[m][kt] = *(const short8*)(pack1 + (size_t)((((w*6+m)<<3)+kt)*64 + lane)*8);

  // b_hh n-part for this lane's 8 hidden units
  f32x4 bn[2];
  #pragma unroll
  for (int nt=0;nt<2;nt++){
    int u = (w<<5) + (nt<<4) + (hi<<2);
    bn[nt] = *(const f32x4*)(b_hh1 + 512 + u);
  }
  if (tid < 256) lngb[tid] = ln_g[tid]; else lngb[tid] = ln_b[tid-256];
  for (int i = tid; i < 2048; i += 512) ((float*)hb[0])[i] = 0.0f;
  f32x4 hr[2]; hr[0] = (f32x4){0,0,0,0}; hr[1] = (f32x4){0,0,0,0};

  // stage xg for t into buf: LDS[row][c] <- xgV[tok(row)][chunk c^(row&7)]
  auto stage = [&](int tt, int buf){
    #pragma unroll
    for (int k=0;k<3;k++){
      int c = k*512 + tid;                 // 16B-chunk index, 96 per row
      int row = c/96, cc = c - row*96;
      int tok = token[tt*128 + b0 + row];
      short8 v = *(const short8*)(xgV + (size_t)tok*768 + (size_t)((cc ^ (row&7))<<3));
      *(short8*)(xgb[buf] + (size_t)c*16) = v;
    }
  };
  stage(0, 0);
  __syncthreads();

  for (int t=0; t<1024; t++){
    const int cur = t & 1, nxt = cur ^ 1;
    if (t < 1023) stage(t+1, nxt);

    f32x4 acc[6];
    #pragma unroll
    for (int m=0;m<6;m++) acc[m] = (f32x4){0,0,0,0};
    #pragma unroll
    for (int kt=0;kt<8;kt++){
      int byte = (col<<9) + (kt<<6) + (hi<<4);
      byte ^= (col&7)<<4;
      short8 hf = *(const short8*)(hb[cur] + byte);
      #pragma unroll
      for (int m=0;m<6;m++)
        acc[m] = __builtin_amdgcn_mfma_f32_16x16x32_bf16(wf[m][kt], hf, acc[m], 0, 0, 0);
    }

    float s1 = 0.f, s2 = 0.f;
    #pragma unroll
    for (int nt=0;nt<2;nt++){
      int ub = (w<<5) + (nt<<4) + (hi<<2);
      // xg reads (gates ub, 256+ub, 512+ub), 4 consecutive bf16 each
      int gb;
      gb = ub;      u64 xr8 = *(const u64*)(xgb[cur] + col*1536 + ((((gb>>3)^(col&7)))<<4) + ((gb&7)<<1));
      gb = 256+ub;  u64 xz8 = *(const u64*)(xgb[cur] + col*1536 + ((((gb>>3)^(col&7)))<<4) + ((gb&7)<<1));
      gb = 512+ub;  u64 xn8 = *(const u64*)(xgb[cur] + col*1536 + ((((gb>>3)^(col&7)))<<4) + ((gb&7)<<1));
      #pragma unroll
      for (int j=0;j<4;j++){
        float xr = bf2f((unsigned short)(xr8 >> (16*j)));
        float xz = bf2f((unsigned short)(xz8 >> (16*j)));
        float xn = bf2f((unsigned short)(xn8 >> (16*j)));
        float r  = sigm(xr + acc[nt][j]);            // b_ih + b_hh_r folded in xgV
        float z  = sigm(xz + acc[2+nt][j]);
        float nn = tanh_(xn + r*(acc[4+nt][j] + bn[nt][j]));
        float h  = nn + z*(hr[nt][j] - nn);
        hr[nt][j] = h;
        s1 += h; s2 += h*h;
      }
      u64 pk = pack4(hr[nt][0], hr[nt][1], hr[nt][2], hr[nt][3]);
      int wb = (col<<9) + (ub<<1);
      wb ^= (col&7)<<4;
      *(u64*)(hb[nxt] + wb) = pk;
    }
    s1 += __shfl_xor(s1, 16); s1 += __shfl_xor(s1, 32);
    s2 += __shfl_xor(s2, 16); s2 += __shfl_xor(s2, 32);
    if (hi == 0){ scr[cur][col][w][0] = s1; scr[cur][col][w][1] = s2; }
    __syncthreads();

    float S1 = 0.f, S2 = 0.f;
    #pragma unroll
    for (int ww=0; ww<8; ww++){ S1 += scr[cur][col][ww][0]; S2 += scr[cur][col][ww][1]; }
    float mu  = S1 * (1.0f/256.0f);
    float var = S2 * (1.0f/256.0f) - mu*mu;
    float rs  = rsqrtf(var + 256.0f);                // faithful eps=256
    #pragma unroll
    for (int nt=0;nt<2;nt++){
      int ub = (w<<5) + (nt<<4) + (hi<<2);
      f32x4 g4 = *(const f32x4*)&lngb[ub];
      f32x4 e4 = *(const f32x4*)&lngb[256+ub];
      u64 pk = pack4((hr[nt][0]-mu)*rs*g4[0] + e4[0],
                     (hr[nt][1]-mu)*rs*g4[1] + e4[1],
                     (hr[nt][2]-mu)*rs*g4[2] + e4[2],
                     (hr[nt][3]-mu)*rs*g4[3] + e4[3]);
      *(u64*)(hn + (size_t)(t*128 + b0 + col)*256 + ub) = pk;
    }
  }
}

// =====================================================================
// K3: xg2 = hn @ [w_ih2f; w_ih2b]^T  (pure matmul; biases added in scan2)
// 512 wgs x 8 waves; waves 0-3 -> fwd gates, 4-7 -> bwd. W in 192 VGPRs.
// Each wg covers 16 consecutive TB-tiles of 16 rows.
// =====================================================================
__launch_bounds__(512, 2)
__global__ void k_k3(const unsigned short* __restrict__ hn,
                     const unsigned short* __restrict__ pack2,
                     unsigned short* __restrict__ xg2f,
                     unsigned short* __restrict__ xg2b)
{
  const int tid = threadIdx.x;
  const int w = tid>>6, lane = tid&63, hi = lane>>4, col = lane&15;
  short8 wf[6][8];
  #pragma unroll
  for (int m=0;m<6;m++)
    #pragma unroll
    for (int kt=0;kt<8;kt++)
      wf[m][kt] = *(const short8*)(pack2 + (size_t)((((w*6+m)<<3)+kt)*64 + lane)*8);
  const int dir = w >> 2;
  unsigned short* dst = dir ? xg2b : xg2f;

  for (int it=0; it<16; it++){
    int tb0 = blockIdx.x*256 + it*16;
    const unsigned short* hrow = hn + (size_t)(tb0 + col)*256;
    f32x4 acc[6];
    #pragma unroll
    for (int m=0;m<6;m++) acc[m] = (f32x4){0,0,0,0};
    #pragma unroll
    for (int h2=0; h2<2; h2++){
      short8 bf[4];
      #pragma unroll
      for (int i=0;i<4;i++) bf[i] = *(const short8*)(hrow + (((h2<<2)+i)<<5) + (hi<<3));
      #pragma unroll
      for (int i=0;i<4;i++)
        #pragma unroll
        for (int m=0;m<6;m++)
          acc[m] = __builtin_amdgcn_mfma_f32_16x16x32_bf16(wf[m][(h2<<2)+i], bf[i], acc[m], 0, 0, 0);
    }
    #pragma unroll
    for (int m=0;m<6;m++){
      int Gl = 96*w + (m<<4) + (hi<<2) - dir*384;
      u64 pk = pack4(acc[m][0], acc[m][1], acc[m][2], acc[m][3]);
      *(u64*)(dst + (size_t)(tb0 + col)*384 + Gl) = pk;
    }
  }
}

// =====================================================================
// K4: layer-2 scans, fwd+bwd concurrent. 16 wgs (8 fwd, 8 bwd) x 8 waves.
// Wave w owns hidden block 16w; w_hh2 in 48 VGPRs/lane. Output fp32.
// =====================================================================
__launch_bounds__(512, 2)
__global__ void k_scan2(const unsigned short* __restrict__ xg2f,
                        const unsigned short* __restrict__ xg2b,
                        const unsigned short* __restrict__ pack3,
                        const float* __restrict__ b_ih2f, const float* __restrict__ b_hh2f,
                        const float* __restrict__ b_ih2b, const float* __restrict__ b_hh2b,
                        float* __restrict__ out)
{
  __shared__ __align__(16) char hb[2][4096];     // [16 batch][128] bf16, swizzled
  const int tid = threadIdx.x;
  const int w = tid>>6, lane = tid&63, hi = lane>>4, col = lane&15;
  const int blk = blockIdx.x;
  const int dir = blk >> 3;
  const int b0  = (blk & 7) * 16;
  const unsigned short* xg = dir ? xg2b : xg2f;
  const float* bi = dir ? b_ih2b : b_ih2f;
  const float* bh = dir ? b_hh2b : b_hh2f;

  short8 wf[3][4];
  #pragma unroll
  for (int m=0;m<3;m++)
    #pragma unroll
    for (int kt=0;kt<4;kt++)
      wf[m][kt] = *(const short8*)(pack3 + (size_t)(((dir*96 + w*12 + (m<<2) + kt))*64 + lane)*8);

  const int u = (w<<4) + (hi<<2);
  f32x4 bir = *(const f32x4*)(bi + u),        bhr = *(const f32x4*)(bh + u);
  f32x4 biz = *(const f32x4*)(bi + 128 + u),  bhz = *(const f32x4*)(bh + 128 + u);
  f32x4 bin = *(const f32x4*)(bi + 256 + u),  bhn = *(const f32x4*)(bh + 256 + u);
  f32x4 bcr = bir + bhr, bcz = biz + bhz;

  for (int i = tid; i < 1024; i += 512) ((float*)hb[0])[i] = 0.0f;
  f32x4 hcur = (f32x4){0,0,0,0};

  // prefetch xg for step 0
  int te0 = dir ? 1023 : 0;
  const unsigned short* p0 = xg + (size_t)(te0*128 + b0 + col)*384;
  u64 xr_n = *(const u64*)(p0 + u);
  u64 xz_n = *(const u64*)(p0 + 128 + u);
  u64 xn_n = *(const u64*)(p0 + 256 + u);
  __syncthreads();

  for (int t=0; t<1024; t++){
    const int cur = t & 1, nxt = cur ^ 1;
    u64 xr = xr_n, xz = xz_n, xn = xn_n;
    if (t < 1023){
      int te1 = dir ? (1022 - t) : (t + 1);
      const unsigned short* p = xg + (size_t)(te1*128 + b0 + col)*384;
      xr_n = *(const u64*)(p + u);
      xz_n = *(const u64*)(p + 128 + u);
      xn_n = *(const u64*)(p + 256 + u);
    }
    f32x4 acc[3];
    #pragma unroll
    for (int m=0;m<3;m++) acc[m] = (f32x4){0,0,0,0};
    #pragma unroll
    for (int kt=0;kt<4;kt++){
      int byte = (col<<8) + (kt<<6) + (hi<<4);
      byte ^= (col&7)<<4;
      short8 hf = *(const short8*)(hb[cur] + byte);
      #pragma unroll
      for (int m=0;m<3;m++)
        acc[m] = __builtin_amdgcn_mfma_f32_16x16x32_bf16(wf[m][kt], hf, acc[m], 0, 0, 0);
    }
    const int te = dir ? (1023 - t) : t;
    f32x4 hnew;
    #pragma unroll
    for (int j=0;j<4;j++){
      float r  = sigm(bf2f((unsigned short)(xr >> (16*j))) + bcr[j] + acc[0][j]);
      float z  = sigm(bf2f((unsigned short)(xz >> (16*j))) + bcz[j] + acc[1][j]);
      float nn = tanh_(bf2f((unsigned short)(xn >> (16*j))) + bin[j] + r*(acc[2][j] + bhn[j]));
      hnew[j] = nn + z*(hcur[j] - nn);
    }
    hcur = hnew;
    *(f32x4*)(out + (size_t)(te*128 + b0 + col)*256 + dir*128 + u) = hnew;
    u64 pk = pack4(hnew[0], hnew[1], hnew[2], hnew[3]);
    int wb = (col<<8) + (u<<1);
    wb ^= (col&7)<<4;
    *(u64*)(hb[nxt] + wb) = pk;
    __syncthreads();
  }
}

// =====================================================================
extern "C" void kernel_launch(void* const* d_in, const int* in_sizes, int n_in,
                              void* d_out, int out_size, void* d_ws, size_t ws_size,
                              hipStream_t stream)
{
  (void)in_sizes; (void)n_in; (void)out_size; (void)ws_size;
  const int*   token  = (const int*)  d_in[0];
  const float* emb    = (const float*)d_in[1];
  const float* w_ih1  = (const float*)d_in[2];
  const float* w_hh1  = (const float*)d_in[3];
  const float* b_ih1  = (const float*)d_in[4];
  const float* b_hh1  = (const float*)d_in[5];
  const float* ln_g   = (const float*)d_in[6];
  const float* ln_b   = (const float*)d_in[7];
  const float* w_ih2f = (const float*)d_in[8];
  const float* w_hh2f = (const float*)d_in[9];
  const float* b_ih2f = (const float*)d_in[10];
  const float* b_hh2f = (const float*)d_in[11];
  const float* w_ih2b = (const float*)d_in[12];
  const float* w_hh2b = (const float*)d_in[13];
  const float* b_ih2b = (const float*)d_in[14];
  const float* b_hh2b = (const float*)d_in[15];
  float* out = (float*)d_out;

  char* ws = (char*)d_ws;
  unsigned short* hn    = (unsigned short*)(ws);              //  67,108,864 B
  unsigned short* xg2f  = (unsigned short*)(ws + 67108864);   // 100,663,296 B
  unsigned short* xg2b  = (unsigned short*)(ws + 167772160);  // 100,663,296 B
  unsigned short* xgV   = (unsigned short*)(ws + 268435456);  //     196,608 B
  unsigned short* pack1 = (unsigned short*)(ws + 268632064);  //     393,216 B
  unsigned short* pack2 = (unsigned short*)(ws + 269025280);  //     393,216 B
  unsigned short* pack3 = (unsigned short*)(ws + 269418496);  //     196,608 B
  // total ~257.1 MiB

  hipLaunchKernelGGL(k_pack,  dim3(240), dim3(256), 0, stream,
                     w_hh1, w_ih2f, w_ih2b, w_hh2f, w_hh2b, pack1, pack2, pack3);
  hipLaunchKernelGGL(k_xgv,   dim3(384), dim3(256), 0, stream,
                     emb, w_ih1, b_ih1, b_hh1, xgV);
  hipLaunchKernelGGL(k_scan1, dim3(8),   dim3(512), 0, stream,
                     token, xgV, pack1, b_hh1, ln_g, ln_b, hn);
  hipLaunchKernelGGL(k_k3,    dim3(512), dim3(512), 0, stream,
                     hn, pack2, xg2f, xg2b);
  hipLaunchKernelGGL(k_scan2, dim3(16),  dim3(512), 0, stream,
                     xg2f, xg2b, pack3, b_ih2f, b_hh2f, b_ih2b, b_hh2b, out);
}

// Round 2
// 6083.209 us; speedup vs baseline: 1.2848x; 1.2848x over previous
//
#include <hip/hip_runtime.h>
#include <hip/hip_bf16.h>
#include <stdint.h>

typedef __attribute__((ext_vector_type(8))) short short8;   // 8 bf16 (4 VGPRs) MFMA frag
typedef __attribute__((ext_vector_type(4))) float f32x4;    // MFMA acc
typedef unsigned long long u64;
typedef unsigned int u32;

// ---------- helpers ----------
__device__ __forceinline__ float bf2f(unsigned short s){
  union { float f; u32 u; } v; v.u = ((u32)s) << 16; return v.f;
}
__device__ __forceinline__ unsigned short f2bf(float f){
  u32 u = __float_as_uint(f);
  u32 r = (u + 0x7fffu + ((u >> 16) & 1u)) >> 16;   // RNE
  return (unsigned short)r;
}
__device__ __forceinline__ float sigm(float x){ return 1.0f / (1.0f + __expf(-x)); }
__device__ __forceinline__ float tanh_(float x){ return 1.0f - 2.0f/(__expf(2.0f*x) + 1.0f); }
__device__ __forceinline__ u64 pack4(float a, float b, float c, float d){
  return (u64)f2bf(a) | ((u64)f2bf(b)<<16) | ((u64)f2bf(c)<<32) | ((u64)f2bf(d)<<48);
}
// async global->LDS, 16B per lane; dest must be wave-uniform base + lane*16
__device__ __forceinline__ void gl_lds16(const void* g, void* l){
  __builtin_amdgcn_global_load_lds(
      (const __attribute__((address_space(1))) unsigned int*)g,
      (__attribute__((address_space(3))) unsigned int*)l, 16, 0, 0);
}

// =====================================================================
// K0a: pack weights into MFMA fragment layout (bf16)
//  frag convention (16x16x32): lane l elem j -> [nonK = l&15][k = (l>>4)*8 + j]
// pack1: w_hh1 (768x256)  wave w owns hidden block 32w; tiles m: 0,1=r 2,3=z 4,5=n
// pack2: [w_ih2f; w_ih2b] as 768 G-rows x 256
// pack3: per-dir w_hh2 (384x128), wave w owns hidden block 16w, tiles m=r,z,n
// =====================================================================
__global__ void k_pack(const float* __restrict__ w_hh1,
                       const float* __restrict__ w_ih2f, const float* __restrict__ w_ih2b,
                       const float* __restrict__ w_hh2f, const float* __restrict__ w_hh2b,
                       unsigned short* __restrict__ pack1,
                       unsigned short* __restrict__ pack2,
                       unsigned short* __restrict__ pack3)
{
  int tid = blockIdx.x*256 + threadIdx.x;
  const float* src;
  unsigned short* dst;
  long idx;
  if (tid < 24576){
    int f = tid>>6, l = tid&63;
    int w = f/48, rem = f%48, m = rem>>3, kt = rem&7;
    int g  = ((m>>1)<<8) + (w<<5) + ((m&1)<<4) + (l&15);
    int kb = (kt<<5) + ((l>>4)<<3);
    src = w_hh1 + (size_t)g*256 + kb;
    dst = pack1; idx = tid;
  } else if (tid < 49152){
    int t2 = tid - 24576;
    int f = t2>>6, l = t2&63;
    int w = f/48, rem = f%48, m = rem>>3, kt = rem&7;
    int G  = 96*w + (m<<4) + (l&15);
    int kb = (kt<<5) + ((l>>4)<<3);
    const float* W = (G < 384) ? w_ih2f : w_ih2b;
    src = W + (size_t)(G % 384)*256 + kb;
    dst = pack2; idx = t2;
  } else {
    int t3 = tid - 49152;
    int f = t3>>6, l = t3&63;
    int dir = f/96, r96 = f%96, w = r96/12, r12 = r96%12, m = r12>>2, kt = r12&3;
    int Grow = (m<<7) + (w<<4) + (l&15);
    int kb = (kt<<5) + ((l>>4)<<3);
    src = (dir ? w_hh2b : w_hh2f) + (size_t)Grow*128 + kb;
    dst = pack3; idx = t3;
  }
  u64 lo = (u64)f2bf(src[0]) | ((u64)f2bf(src[1])<<16) | ((u64)f2bf(src[2])<<32) | ((u64)f2bf(src[3])<<48);
  u64 hi = (u64)f2bf(src[4]) | ((u64)f2bf(src[5])<<16) | ((u64)f2bf(src[6])<<32) | ((u64)f2bf(src[7])<<48);
  *(u64*)(dst + (size_t)idx*8)     = lo;
  *(u64*)(dst + (size_t)idx*8 + 4) = hi;
}

// =====================================================================
// K0b: xgV[v][g] = emb[v,:]·w_ih1[g,:] + b_ih1[g] + (g<512 ? b_hh1[g] : 0)
// f32 output, 128x768. (b_hh for r,z folded in; b_hh_n stays separate.)
// =====================================================================
__global__ void k_xgv(const float* __restrict__ emb, const float* __restrict__ w_ih1,
                      const float* __restrict__ b_ih1, const float* __restrict__ b_hh1,
                      float* __restrict__ xgV)
{
  int tid = blockIdx.x*256 + threadIdx.x;        // 98304 total
  int v = tid / 768, g = tid % 768;
  float s = b_ih1[g] + (g < 512 ? b_hh1[g] : 0.0f);
  const f32x4* e4 = (const f32x4*)(emb   + (size_t)v*312);
  const f32x4* w4 = (const f32x4*)(w_ih1 + (size_t)g*312);
  #pragma unroll 4
  for (int i=0;i<78;i++){
    f32x4 a = e4[i], b = w4[i];
    s += a[0]*b[0] + a[1]*b[1] + a[2]*b[2] + a[3]*b[3];
  }
  xgV[tid] = s;
}

// =====================================================================
// K1: layer-1 scan. 8 wgs x 512 thr (8 waves). wg p owns batch [16p,16p+16).
// Wave w owns hidden block u0=32w (gates u0.., 256+u0.., 512+u0..).
// Weights stationary in 192 VGPRs/lane (launch_bounds(512) -> cap 256).
// LDS layouts are [chunk16B][batch] -> conflict-free b128 reads, no swizzle.
// xg staged in f32 via global_load_lds (async, zero staging VGPRs).
// D = mfma(Wfrag, hfrag): row=gate (lane>>4)*4+reg, col=batch lane&15.
// =====================================================================
__launch_bounds__(512)
__global__ void k_scan1(const int* __restrict__ token,
                        const float* __restrict__ xgV,
                        const unsigned short* __restrict__ pack1,
                        const float* __restrict__ b_hh1,
                        const float* __restrict__ ln_g, const float* __restrict__ ln_b,
                        unsigned short* __restrict__ hn)
{
  __shared__ __align__(16) char hb[2][8192];     // [32 chunk][16 batch][8 bf16]
  __shared__ __align__(16) char xgb[2][49152];   // [192 chunk][16 batch][4 f32]
  __shared__ __align__(16) float lngb[512];      // ln_g | ln_b
  __shared__ __align__(16) float bnl[256];       // b_hh1 n-part
  __shared__ __align__(8)  float2 scr[2][8][16]; // [buf][wave][col] partial sums

  const int tid = threadIdx.x;
  const int w = tid>>6, lane = tid&63, hi = lane>>4, col = lane&15;
  const int b0 = blockIdx.x * 16;

  // persistent weight fragments: 6 Mtiles x 8 Ktiles = 192 VGPRs
  short8 wf[6][8];
  #pragma unroll
  for (int m=0;m<6;m++)
    #pragma unroll
    for (int kt=0;kt<8;kt++)
      wf[m][kt] = *(const short8*)(pack1 + (size_t)((((w*6+m)<<3)+kt)*64 + lane)*8);

  if (tid < 256) lngb[tid] = ln_g[tid]; else lngb[tid] = ln_b[tid-256];
  if (tid < 256) bnl[tid] = b_hh1[512 + tid];
  for (int i = tid; i < 2048; i += 512) ((u32*)hb[0])[i] = 0;
  f32x4 hr[2]; hr[0] = (f32x4){0,0,0,0}; hr[1] = (f32x4){0,0,0,0};

  // stage xg(t) into buf: LDS chunk c=k*32+(tid>>4), batch b=tid&15
  auto stage = [&](int tt, int buf){
    int tok = token[tt*128 + b0 + (tid & 15)];
    const char* src = (const char*)xgV + (size_t)tok*3072 + ((tid>>4)<<4);
    char* dst = xgb[buf] + tid*16;
    #pragma unroll
    for (int k=0;k<6;k++)
      gl_lds16(src + k*512, dst + k*8192);
  };
  stage(0, 0);
  __syncthreads();

  for (int t=0; t<1024; t++){
    const int cur = t & 1, nxt = cur ^ 1;
    if (t < 1023) stage(t+1, nxt);

    f32x4 acc[6];
    #pragma unroll
    for (int m=0;m<6;m++) acc[m] = (f32x4){0,0,0,0};
    #pragma unroll
    for (int kt=0;kt<8;kt++){
      short8 hf = *(const short8*)(hb[cur] + ((kt<<2)+hi)*256 + (col<<4));
      #pragma unroll
      for (int m=0;m<6;m++)
        acc[m] = __builtin_amdgcn_mfma_f32_16x16x32_bf16(wf[m][kt], hf, acc[m], 0, 0, 0);
    }

    float s1 = 0.f, s2 = 0.f;
    #pragma unroll
    for (int nt=0;nt<2;nt++){
      const int ub = (w<<5) + (nt<<4) + (hi<<2);
      const char* xb = xgb[cur] + (col<<4);
      f32x4 xr = *(const f32x4*)(xb + (size_t)ub*64);
      f32x4 xz = *(const f32x4*)(xb + (size_t)(256+ub)*64);
      f32x4 xn = *(const f32x4*)(xb + (size_t)(512+ub)*64);
      f32x4 bn4 = *(const f32x4*)(bnl + ub);
      #pragma unroll
      for (int j=0;j<4;j++){
        float r  = sigm(xr[j] + acc[nt][j]);           // b_ih + b_hh_r folded in xgV
        float z  = sigm(xz[j] + acc[2+nt][j]);
        float nn = tanh_(xn[j] + r*(acc[4+nt][j] + bn4[j]));
        float h  = nn + z*(hr[nt][j] - nn);
        hr[nt][j] = h;
        s1 += h; s2 += h*h;
      }
      u64 pk = pack4(hr[nt][0], hr[nt][1], hr[nt][2], hr[nt][3]);
      *(u64*)(hb[nxt] + (ub>>3)*256 + (col<<4) + ((hi&1)<<3)) = pk;
    }
    s1 += __shfl_xor(s1, 16); s1 += __shfl_xor(s1, 32);
    s2 += __shfl_xor(s2, 16); s2 += __shfl_xor(s2, 32);
    if (hi == 0){ scr[cur][w][col] = make_float2(s1, s2); }
    __syncthreads();

    float S1 = 0.f, S2 = 0.f;
    #pragma unroll
    for (int ww=0; ww<8; ww++){ float2 v = scr[cur][ww][col]; S1 += v.x; S2 += v.y; }
    float mu  = S1 * (1.0f/256.0f);
    float var = S2 * (1.0f/256.0f) - mu*mu;
    float rs  = rsqrtf(var + 256.0f);                  // faithful eps=256
    #pragma unroll
    for (int nt=0;nt<2;nt++){
      const int ub = (w<<5) + (nt<<4) + (hi<<2);
      f32x4 g4 = *(const f32x4*)&lngb[ub];
      f32x4 e4 = *(const f32x4*)&lngb[256+ub];
      u64 pk = pack4((hr[nt][0]-mu)*rs*g4[0] + e4[0],
                     (hr[nt][1]-mu)*rs*g4[1] + e4[1],
                     (hr[nt][2]-mu)*rs*g4[2] + e4[2],
                     (hr[nt][3]-mu)*rs*g4[3] + e4[3]);
      *(u64*)(hn + (size_t)(t*128 + b0 + col)*256 + ub) = pk;
    }
  }
}

// =====================================================================
// K3: xg2 = hn @ [w_ih2f; w_ih2b]^T  (pure matmul; biases added in scan2)
// 512 wgs x 8 waves; waves 0-3 -> fwd gates, 4-7 -> bwd. W in 192 VGPRs.
// =====================================================================
__launch_bounds__(512)
__global__ void k_k3(const unsigned short* __restrict__ hn,
                     const unsigned short* __restrict__ pack2,
                     unsigned short* __restrict__ xg2f,
                     unsigned short* __restrict__ xg2b)
{
  const int tid = threadIdx.x;
  const int w = tid>>6, lane = tid&63, hi = lane>>4, col = lane&15;
  short8 wf[6][8];
  #pragma unroll
  for (int m=0;m<6;m++)
    #pragma unroll
    for (int kt=0;kt<8;kt++)
      wf[m][kt] = *(const short8*)(pack2 + (size_t)((((w*6+m)<<3)+kt)*64 + lane)*8);
  const int dir = w >> 2;
  unsigned short* dst = dir ? xg2b : xg2f;

  for (int it=0; it<16; it++){
    int tb0 = blockIdx.x*256 + it*16;
    const unsigned short* hrow = hn + (size_t)(tb0 + col)*256;
    f32x4 acc[6];
    #pragma unroll
    for (int m=0;m<6;m++) acc[m] = (f32x4){0,0,0,0};
    #pragma unroll
    for (int h2=0; h2<2; h2++){
      short8 bf[4];
      #pragma unroll
      for (int i=0;i<4;i++) bf[i] = *(const short8*)(hrow + (((h2<<2)+i)<<5) + (hi<<3));
      #pragma unroll
      for (int i=0;i<4;i++)
        #pragma unroll
        for (int m=0;m<6;m++)
          acc[m] = __builtin_amdgcn_mfma_f32_16x16x32_bf16(wf[m][(h2<<2)+i], bf[i], acc[m], 0, 0, 0);
    }
    #pragma unroll
    for (int m=0;m<6;m++){
      int Gl = 96*w + (m<<4) + (hi<<2) - dir*384;
      u64 pk = pack4(acc[m][0], acc[m][1], acc[m][2], acc[m][3]);
      *(u64*)(dst + (size_t)(tb0 + col)*384 + Gl) = pk;
    }
  }
}

// =====================================================================
// K4: layer-2 scans, fwd+bwd concurrent. 16 wgs (8 fwd, 8 bwd) x 8 waves.
// Wave w owns hidden block 16w; w_hh2 in 48 VGPRs/lane. Output fp32.
// hb layout [chunk16B][batch] -> conflict-free.
// =====================================================================
__launch_bounds__(512)
__global__ void k_scan2(const unsigned short* __restrict__ xg2f,
                        const unsigned short* __restrict__ xg2b,
                        const unsigned short* __restrict__ pack3,
                        const float* __restrict__ b_ih2f, const float* __restrict__ b_hh2f,
                        const float* __restrict__ b_ih2b, const float* __restrict__ b_hh2b,
                        float* __restrict__ out)
{
  __shared__ __align__(16) char hb[2][4096];     // [16 chunk][16 batch][8 bf16]
  const int tid = threadIdx.x;
  const int w = tid>>6, lane = tid&63, hi = lane>>4, col = lane&15;
  const int blk = blockIdx.x;
  const int dir = blk >> 3;
  const int b0  = (blk & 7) * 16;
  const unsigned short* xg = dir ? xg2b : xg2f;
  const float* bi = dir ? b_ih2b : b_ih2f;
  const float* bh = dir ? b_hh2b : b_hh2f;

  short8 wf[3][4];
  #pragma unroll
  for (int m=0;m<3;m++)
    #pragma unroll
    for (int kt=0;kt<4;kt++)
      wf[m][kt] = *(const short8*)(pack3 + (size_t)(((dir*96 + w*12 + (m<<2) + kt))*64 + lane)*8);

  const int u = (w<<4) + (hi<<2);
  f32x4 bir = *(const f32x4*)(bi + u),        bhr = *(const f32x4*)(bh + u);
  f32x4 biz = *(const f32x4*)(bi + 128 + u),  bhz = *(const f32x4*)(bh + 128 + u);
  f32x4 bin = *(const f32x4*)(bi + 256 + u),  bhn = *(const f32x4*)(bh + 256 + u);
  f32x4 bcr = bir + bhr, bcz = biz + bhz;

  for (int i = tid; i < 1024; i += 512) ((u32*)hb[0])[i] = 0;
  f32x4 hcur = (f32x4){0,0,0,0};

  // prefetch xg for step 0
  int te0 = dir ? 1023 : 0;
  const unsigned short* p0 = xg + (size_t)(te0*128 + b0 + col)*384;
  u64 xr_n = *(const u64*)(p0 + u);
  u64 xz_n = *(const u64*)(p0 + 128 + u);
  u64 xn_n = *(const u64*)(p0 + 256 + u);
  __syncthreads();

  for (int t=0; t<1024; t++){
    const int cur = t & 1, nxt = cur ^ 1;
    u64 xr = xr_n, xz = xz_n, xn = xn_n;
    if (t < 1023){
      int te1 = dir ? (1022 - t) : (t + 1);
      const unsigned short* p = xg + (size_t)(te1*128 + b0 + col)*384;
      xr_n = *(const u64*)(p + u);
      xz_n = *(const u64*)(p + 128 + u);
      xn_n = *(const u64*)(p + 256 + u);
    }
    f32x4 acc[3];
    #pragma unroll
    for (int m=0;m<3;m++) acc[m] = (f32x4){0,0,0,0};
    #pragma unroll
    for (int kt=0;kt<4;kt++){
      short8 hf = *(const short8*)(hb[cur] + ((kt<<2)+hi)*256 + (col<<4));
      #pragma unroll
      for (int m=0;m<3;m++)
        acc[m] = __builtin_amdgcn_mfma_f32_16x16x32_bf16(wf[m][kt], hf, acc[m], 0, 0, 0);
    }
    const int te = dir ? (1023 - t) : t;
    f32x4 hnew;
    #pragma unroll
    for (int j=0;j<4;j++){
      float r  = sigm(bf2f((unsigned short)(xr >> (16*j))) + bcr[j] + acc[0][j]);
      float z  = sigm(bf2f((unsigned short)(xz >> (16*j))) + bcz[j] + acc[1][j]);
      float nn = tanh_(bf2f((unsigned short)(xn >> (16*j))) + bin[j] + r*(acc[2][j] + bhn[j]));
      hnew[j] = nn + z*(hcur[j] - nn);
    }
    hcur = hnew;
    *(f32x4*)(out + (size_t)(te*128 + b0 + col)*256 + dir*128 + u) = hnew;
    u64 pk = pack4(hnew[0], hnew[1], hnew[2], hnew[3]);
    *(u64*)(hb[nxt] + ((u>>3))*256 + (col<<4) + ((hi&1)<<3)) = pk;
    __syncthreads();
  }
}

// =====================================================================
extern "C" void kernel_launch(void* const* d_in, const int* in_sizes, int n_in,
                              void* d_out, int out_size, void* d_ws, size_t ws_size,
                              hipStream_t stream)
{
  (void)in_sizes; (void)n_in; (void)out_size; (void)ws_size;
  const int*   token  = (const int*)  d_in[0];
  const float* emb    = (const float*)d_in[1];
  const float* w_ih1  = (const float*)d_in[2];
  const float* w_hh1  = (const float*)d_in[3];
  const float* b_ih1  = (const float*)d_in[4];
  const float* b_hh1  = (const float*)d_in[5];
  const float* ln_g   = (const float*)d_in[6];
  const float* ln_b   = (const float*)d_in[7];
  const float* w_ih2f = (const float*)d_in[8];
  const float* w_hh2f = (const float*)d_in[9];
  const float* b_ih2f = (const float*)d_in[10];
  const float* b_hh2f = (const float*)d_in[11];
  const float* w_ih2b = (const float*)d_in[12];
  const float* w_hh2b = (const float*)d_in[13];
  const float* b_ih2b = (const float*)d_in[14];
  const float* b_hh2b = (const float*)d_in[15];
  float* out = (float*)d_out;

  char* ws = (char*)d_ws;
  unsigned short* hn    = (unsigned short*)(ws);              //  67,108,864 B
  unsigned short* xg2f  = (unsigned short*)(ws + 67108864);   // 100,663,296 B
  unsigned short* xg2b  = (unsigned short*)(ws + 167772160);  // 100,663,296 B
  // xgV (f32, 393,216 B) aliases the START of the xg2b region: it is consumed
  // by k_scan1, which completes before k_k3 writes xg2b. Keeps ws footprint
  // identical to the previously-passing layout.
  float*          xgV   = (float*)(ws + 167772160);
  unsigned short* pack1 = (unsigned short*)(ws + 268632064);  //     393,216 B
  unsigned short* pack2 = (unsigned short*)(ws + 269025280);  //     393,216 B
  unsigned short* pack3 = (unsigned short*)(ws + 269418496);  //     196,608 B

  hipLaunchKernelGGL(k_pack,  dim3(240), dim3(256), 0, stream,
                     w_hh1, w_ih2f, w_ih2b, w_hh2f, w_hh2b, pack1, pack2, pack3);
  hipLaunchKernelGGL(k_xgv,   dim3(384), dim3(256), 0, stream,
                     emb, w_ih1, b_ih1, b_hh1, xgV);
  hipLaunchKernelGGL(k_scan1, dim3(8),   dim3(512), 0, stream,
                     token, xgV, pack1, b_hh1, ln_g, ln_b, hn);
  hipLaunchKernelGGL(k_k3,    dim3(512), dim3(512), 0, stream,
                     hn, pack2, xg2f, xg2b);
  hipLaunchKernelGGL(k_scan2, dim3(16),  dim3(512), 0, stream,
                     xg2f, xg2b, pack3, b_ih2f, b_hh2f, b_ih2b, b_hh2b, out);
}

// Round 3
// 6080.577 us; speedup vs baseline: 1.2854x; 1.0004x over previous
//
#include <hip/hip_runtime.h>
#include <hip/hip_bf16.h>
#include <stdint.h>

typedef __attribute__((ext_vector_type(8))) short short8;   // 8 bf16 (4 VGPRs) MFMA frag
typedef __attribute__((ext_vector_type(4))) float f32x4;    // MFMA acc
typedef unsigned long long u64;
typedef unsigned int u32;

// ---------- helpers ----------
__device__ __forceinline__ float bf2f(unsigned short s){
  union { float f; u32 u; } v; v.u = ((u32)s) << 16; return v.f;
}
__device__ __forceinline__ unsigned short f2bf(float f){
  u32 u = __float_as_uint(f);
  u32 r = (u + 0x7fffu + ((u >> 16) & 1u)) >> 16;   // RNE
  return (unsigned short)r;
}
__device__ __forceinline__ float sigm(float x){ return 1.0f / (1.0f + __expf(-x)); }
__device__ __forceinline__ float tanh_(float x){ return 1.0f - 2.0f/(__expf(2.0f*x) + 1.0f); }
__device__ __forceinline__ u64 pack4(float a, float b, float c, float d){
  return (u64)f2bf(a) | ((u64)f2bf(b)<<16) | ((u64)f2bf(c)<<32) | ((u64)f2bf(d)<<48);
}
// async global->LDS, 16B per lane; dest must be wave-uniform base + lane*16
__device__ __forceinline__ void gl_lds16(const void* g, void* l){
  __builtin_amdgcn_global_load_lds(
      (const __attribute__((address_space(1))) unsigned int*)g,
      (__attribute__((address_space(3))) unsigned int*)l, 16, 0, 0);
}

// =====================================================================
// K0a: pack weights into MFMA fragment layout (bf16)
//  frag convention (16x16x32): lane l elem j -> [nonK = l&15][k = (l>>4)*8 + j]
// pack1: w_hh1 (768x256)  wave w owns hidden block 32w; tiles m: 0,1=r 2,3=z 4,5=n
// pack2: [w_ih2f; w_ih2b] as 768 G-rows x 256
// pack3: per-dir w_hh2 (384x128), wave w owns hidden block 16w, tiles m=r,z,n
// =====================================================================
__global__ void k_pack(const float* __restrict__ w_hh1,
                       const float* __restrict__ w_ih2f, const float* __restrict__ w_ih2b,
                       const float* __restrict__ w_hh2f, const float* __restrict__ w_hh2b,
                       unsigned short* __restrict__ pack1,
                       unsigned short* __restrict__ pack2,
                       unsigned short* __restrict__ pack3)
{
  int tid = blockIdx.x*256 + threadIdx.x;
  const float* src;
  unsigned short* dst;
  long idx;
  if (tid < 24576){
    int f = tid>>6, l = tid&63;
    int w = f/48, rem = f%48, m = rem>>3, kt = rem&7;
    int g  = ((m>>1)<<8) + (w<<5) + ((m&1)<<4) + (l&15);
    int kb = (kt<<5) + ((l>>4)<<3);
    src = w_hh1 + (size_t)g*256 + kb;
    dst = pack1; idx = tid;
  } else if (tid < 49152){
    int t2 = tid - 24576;
    int f = t2>>6, l = t2&63;
    int w = f/48, rem = f%48, m = rem>>3, kt = rem&7;
    int G  = 96*w + (m<<4) + (l&15);
    int kb = (kt<<5) + ((l>>4)<<3);
    const float* W = (G < 384) ? w_ih2f : w_ih2b;
    src = W + (size_t)(G % 384)*256 + kb;
    dst = pack2; idx = t2;
  } else {
    int t3 = tid - 49152;
    int f = t3>>6, l = t3&63;
    int dir = f/96, r96 = f%96, w = r96/12, r12 = r96%12, m = r12>>2, kt = r12&3;
    int Grow = (m<<7) + (w<<4) + (l&15);
    int kb = (kt<<5) + ((l>>4)<<3);
    src = (dir ? w_hh2b : w_hh2f) + (size_t)Grow*128 + kb;
    dst = pack3; idx = t3;
  }
  u64 lo = (u64)f2bf(src[0]) | ((u64)f2bf(src[1])<<16) | ((u64)f2bf(src[2])<<32) | ((u64)f2bf(src[3])<<48);
  u64 hi = (u64)f2bf(src[4]) | ((u64)f2bf(src[5])<<16) | ((u64)f2bf(src[6])<<32) | ((u64)f2bf(src[7])<<48);
  *(u64*)(dst + (size_t)idx*8)     = lo;
  *(u64*)(dst + (size_t)idx*8 + 4) = hi;
}

// =====================================================================
// K0b: xgV[v][g] = emb[v,:]·w_ih1[g,:] + b_ih1[g] + (g<512 ? b_hh1[g] : 0)
// f32 output, 128x768. (b_hh for r,z folded in; b_hh_n stays separate.)
// =====================================================================
__global__ void k_xgv(const float* __restrict__ emb, const float* __restrict__ w_ih1,
                      const float* __restrict__ b_ih1, const float* __restrict__ b_hh1,
                      float* __restrict__ xgV)
{
  int tid = blockIdx.x*256 + threadIdx.x;        // 98304 total
  int v = tid / 768, g = tid % 768;
  float s = b_ih1[g] + (g < 512 ? b_hh1[g] : 0.0f);
  const f32x4* e4 = (const f32x4*)(emb   + (size_t)v*312);
  const f32x4* w4 = (const f32x4*)(w_ih1 + (size_t)g*312);
  #pragma unroll 4
  for (int i=0;i<78;i++){
    f32x4 a = e4[i], b = w4[i];
    s += a[0]*b[0] + a[1]*b[1] + a[2]*b[2] + a[3]*b[3];
  }
  xgV[tid] = s;
}

// =====================================================================
// K1: layer-1 scan. 8 wgs x 512 thr (8 waves). wg p owns batch [16p,16p+16).
// Wave w owns hidden block u0=32w (gates u0.., 256+u0.., 512+u0..).
// Weights stationary in 192 VGPRs/lane. amdgpu_waves_per_eu(1,2) sets the
// register budget to 256/wave so wf does NOT spill (round-2 post-mortem:
// default scheduler targeted 4 waves/EU -> 128 regs -> 393KB/step refetch).
// LDS layouts are [chunk16B][batch] -> conflict-free b128 reads, no swizzle.
// xg staged in f32 via global_load_lds (async, zero staging VGPRs).
// D = mfma(Wfrag, hfrag): row=gate (lane>>4)*4+reg, col=batch lane&15.
// =====================================================================
__attribute__((amdgpu_waves_per_eu(1,2)))
__launch_bounds__(512)
__global__ void k_scan1(const int* __restrict__ token,
                        const float* __restrict__ xgV,
                        const unsigned short* __restrict__ pack1,
                        const float* __restrict__ b_hh1,
                        const float* __restrict__ ln_g, const float* __restrict__ ln_b,
                        unsigned short* __restrict__ hn)
{
  __shared__ __align__(16) char hb[2][8192];     // [32 chunk][16 batch][8 bf16]
  __shared__ __align__(16) char xgb[2][49152];   // [192 chunk][16 batch][4 f32]
  __shared__ __align__(16) float lngb[512];      // ln_g | ln_b
  __shared__ __align__(16) float bnl[256];       // b_hh1 n-part
  __shared__ __align__(8)  float2 scr[2][8][16]; // [buf][wave][col] partial sums

  const int tid = threadIdx.x;
  const int w = tid>>6, lane = tid&63, hi = lane>>4, col = lane&15;
  const int b0 = blockIdx.x * 16;

  // persistent weight fragments: 6 Mtiles x 8 Ktiles = 192 VGPRs
  short8 wf[6][8];
  #pragma unroll
  for (int m=0;m<6;m++)
    #pragma unroll
    for (int kt=0;kt<8;kt++)
      wf[m][kt] = *(const short8*)(pack1 + (size_t)((((w*6+m)<<3)+kt)*64 + lane)*8);

  if (tid < 256) lngb[tid] = ln_g[tid]; else lngb[tid] = ln_b[tid-256];
  if (tid < 256) bnl[tid] = b_hh1[512 + tid];
  for (int i = tid; i < 2048; i += 512) ((u32*)hb[0])[i] = 0;
  f32x4 hr[2]; hr[0] = (f32x4){0,0,0,0}; hr[1] = (f32x4){0,0,0,0};

  // stage xg(t) into buf: LDS chunk c=k*32+(tid>>4), batch b=tid&15
  auto stage = [&](int tt, int buf){
    int tok = token[tt*128 + b0 + (tid & 15)];
    const char* src = (const char*)xgV + (size_t)tok*3072 + ((tid>>4)<<4);
    char* dst = xgb[buf] + tid*16;
    #pragma unroll
    for (int k=0;k<6;k++)
      gl_lds16(src + k*512, dst + k*8192);
  };
  stage(0, 0);
  __syncthreads();

  for (int t=0; t<1024; t++){
    const int cur = t & 1, nxt = cur ^ 1;
    if (t < 1023) stage(t+1, nxt);

    f32x4 acc[6];
    #pragma unroll
    for (int m=0;m<6;m++) acc[m] = (f32x4){0,0,0,0};
    #pragma unroll
    for (int kt=0;kt<8;kt++){
      short8 hf = *(const short8*)(hb[cur] + ((kt<<2)+hi)*256 + (col<<4));
      #pragma unroll
      for (int m=0;m<6;m++)
        acc[m] = __builtin_amdgcn_mfma_f32_16x16x32_bf16(wf[m][kt], hf, acc[m], 0, 0, 0);
    }

    float s1 = 0.f, s2 = 0.f;
    #pragma unroll
    for (int nt=0;nt<2;nt++){
      const int ub = (w<<5) + (nt<<4) + (hi<<2);
      const char* xb = xgb[cur] + (col<<4);
      f32x4 xr = *(const f32x4*)(xb + (size_t)ub*64);
      f32x4 xz = *(const f32x4*)(xb + (size_t)(256+ub)*64);
      f32x4 xn = *(const f32x4*)(xb + (size_t)(512+ub)*64);
      f32x4 bn4 = *(const f32x4*)(bnl + ub);
      #pragma unroll
      for (int j=0;j<4;j++){
        float r  = sigm(xr[j] + acc[nt][j]);           // b_ih + b_hh_r folded in xgV
        float z  = sigm(xz[j] + acc[2+nt][j]);
        float nn = tanh_(xn[j] + r*(acc[4+nt][j] + bn4[j]));
        float h  = nn + z*(hr[nt][j] - nn);
        hr[nt][j] = h;
        s1 += h; s2 += h*h;
      }
      u64 pk = pack4(hr[nt][0], hr[nt][1], hr[nt][2], hr[nt][3]);
      *(u64*)(hb[nxt] + (ub>>3)*256 + (col<<4) + ((hi&1)<<3)) = pk;
    }
    s1 += __shfl_xor(s1, 16); s1 += __shfl_xor(s1, 32);
    s2 += __shfl_xor(s2, 16); s2 += __shfl_xor(s2, 32);
    if (hi == 0){ scr[cur][w][col] = make_float2(s1, s2); }
    __syncthreads();

    float S1 = 0.f, S2 = 0.f;
    #pragma unroll
    for (int ww=0; ww<8; ww++){ float2 v = scr[cur][ww][col]; S1 += v.x; S2 += v.y; }
    float mu  = S1 * (1.0f/256.0f);
    float var = S2 * (1.0f/256.0f) - mu*mu;
    float rs  = rsqrtf(var + 256.0f);                  // faithful eps=256
    #pragma unroll
    for (int nt=0;nt<2;nt++){
      const int ub = (w<<5) + (nt<<4) + (hi<<2);
      f32x4 g4 = *(const f32x4*)&lngb[ub];
      f32x4 e4 = *(const f32x4*)&lngb[256+ub];
      u64 pk = pack4((hr[nt][0]-mu)*rs*g4[0] + e4[0],
                     (hr[nt][1]-mu)*rs*g4[1] + e4[1],
                     (hr[nt][2]-mu)*rs*g4[2] + e4[2],
                     (hr[nt][3]-mu)*rs*g4[3] + e4[3]);
      *(u64*)(hn + (size_t)(t*128 + b0 + col)*256 + ub) = pk;
    }
  }
}

// =====================================================================
// K3: xg2 = hn @ [w_ih2f; w_ih2b]^T  (pure matmul; biases added in scan2)
// 512 wgs x 8 waves; waves 0-3 -> fwd gates, 4-7 -> bwd. W in 192 VGPRs
// (waves_per_eu(1,2) -> 256-reg budget, no spill).
// =====================================================================
__attribute__((amdgpu_waves_per_eu(1,2)))
__launch_bounds__(512)
__global__ void k_k3(const unsigned short* __restrict__ hn,
                     const unsigned short* __restrict__ pack2,
                     unsigned short* __restrict__ xg2f,
                     unsigned short* __restrict__ xg2b)
{
  const int tid = threadIdx.x;
  const int w = tid>>6, lane = tid&63, hi = lane>>4, col = lane&15;
  short8 wf[6][8];
  #pragma unroll
  for (int m=0;m<6;m++)
    #pragma unroll
    for (int kt=0;kt<8;kt++)
      wf[m][kt] = *(const short8*)(pack2 + (size_t)((((w*6+m)<<3)+kt)*64 + lane)*8);
  const int dir = w >> 2;
  unsigned short* dst = dir ? xg2b : xg2f;

  for (int it=0; it<16; it++){
    int tb0 = blockIdx.x*256 + it*16;
    const unsigned short* hrow = hn + (size_t)(tb0 + col)*256;
    f32x4 acc[6];
    #pragma unroll
    for (int m=0;m<6;m++) acc[m] = (f32x4){0,0,0,0};
    #pragma unroll
    for (int h2=0; h2<2; h2++){
      short8 bf[4];
      #pragma unroll
      for (int i=0;i<4;i++) bf[i] = *(const short8*)(hrow + (((h2<<2)+i)<<5) + (hi<<3));
      #pragma unroll
      for (int i=0;i<4;i++)
        #pragma unroll
        for (int m=0;m<6;m++)
          acc[m] = __builtin_amdgcn_mfma_f32_16x16x32_bf16(wf[m][(h2<<2)+i], bf[i], acc[m], 0, 0, 0);
    }
    #pragma unroll
    for (int m=0;m<6;m++){
      int Gl = 96*w + (m<<4) + (hi<<2) - dir*384;
      u64 pk = pack4(acc[m][0], acc[m][1], acc[m][2], acc[m][3]);
      *(u64*)(dst + (size_t)(tb0 + col)*384 + Gl) = pk;
    }
  }
}

// =====================================================================
// K4: layer-2 scans, fwd+bwd concurrent. 16 wgs (8 fwd, 8 bwd) x 8 waves.
// Wave w owns hidden block 16w; w_hh2 in 48 VGPRs/lane. Output fp32.
// hb layout [chunk16B][batch] -> conflict-free.
// =====================================================================
__launch_bounds__(512)
__global__ void k_scan2(const unsigned short* __restrict__ xg2f,
                        const unsigned short* __restrict__ xg2b,
                        const unsigned short* __restrict__ pack3,
                        const float* __restrict__ b_ih2f, const float* __restrict__ b_hh2f,
                        const float* __restrict__ b_ih2b, const float* __restrict__ b_hh2b,
                        float* __restrict__ out)
{
  __shared__ __align__(16) char hb[2][4096];     // [16 chunk][16 batch][8 bf16]
  const int tid = threadIdx.x;
  const int w = tid>>6, lane = tid&63, hi = lane>>4, col = lane&15;
  const int blk = blockIdx.x;
  const int dir = blk >> 3;
  const int b0  = (blk & 7) * 16;
  const unsigned short* xg = dir ? xg2b : xg2f;
  const float* bi = dir ? b_ih2b : b_ih2f;
  const float* bh = dir ? b_hh2b : b_hh2f;

  short8 wf[3][4];
  #pragma unroll
  for (int m=0;m<3;m++)
    #pragma unroll
    for (int kt=0;kt<4;kt++)
      wf[m][kt] = *(const short8*)(pack3 + (size_t)(((dir*96 + w*12 + (m<<2) + kt))*64 + lane)*8);

  const int u = (w<<4) + (hi<<2);
  f32x4 bir = *(const f32x4*)(bi + u),        bhr = *(const f32x4*)(bh + u);
  f32x4 biz = *(const f32x4*)(bi + 128 + u),  bhz = *(const f32x4*)(bh + 128 + u);
  f32x4 bin = *(const f32x4*)(bi + 256 + u),  bhn = *(const f32x4*)(bh + 256 + u);
  f32x4 bcr = bir + bhr, bcz = biz + bhz;

  for (int i = tid; i < 1024; i += 512) ((u32*)hb[0])[i] = 0;
  f32x4 hcur = (f32x4){0,0,0,0};

  // prefetch xg for step 0
  int te0 = dir ? 1023 : 0;
  const unsigned short* p0 = xg + (size_t)(te0*128 + b0 + col)*384;
  u64 xr_n = *(const u64*)(p0 + u);
  u64 xz_n = *(const u64*)(p0 + 128 + u);
  u64 xn_n = *(const u64*)(p0 + 256 + u);
  __syncthreads();

  for (int t=0; t<1024; t++){
    const int cur = t & 1, nxt = cur ^ 1;
    u64 xr = xr_n, xz = xz_n, xn = xn_n;
    if (t < 1023){
      int te1 = dir ? (1022 - t) : (t + 1);
      const unsigned short* p = xg + (size_t)(te1*128 + b0 + col)*384;
      xr_n = *(const u64*)(p + u);
      xz_n = *(const u64*)(p + 128 + u);
      xn_n = *(const u64*)(p + 256 + u);
    }
    f32x4 acc[3];
    #pragma unroll
    for (int m=0;m<3;m++) acc[m] = (f32x4){0,0,0,0};
    #pragma unroll
    for (int kt=0;kt<4;kt++){
      short8 hf = *(const short8*)(hb[cur] + ((kt<<2)+hi)*256 + (col<<4));
      #pragma unroll
      for (int m=0;m<3;m++)
        acc[m] = __builtin_amdgcn_mfma_f32_16x16x32_bf16(wf[m][kt], hf, acc[m], 0, 0, 0);
    }
    const int te = dir ? (1023 - t) : t;
    f32x4 hnew;
    #pragma unroll
    for (int j=0;j<4;j++){
      float r  = sigm(bf2f((unsigned short)(xr >> (16*j))) + bcr[j] + acc[0][j]);
      float z  = sigm(bf2f((unsigned short)(xz >> (16*j))) + bcz[j] + acc[1][j]);
      float nn = tanh_(bf2f((unsigned short)(xn >> (16*j))) + bin[j] + r*(acc[2][j] + bhn[j]));
      hnew[j] = nn + z*(hcur[j] - nn);
    }
    hcur = hnew;
    *(f32x4*)(out + (size_t)(te*128 + b0 + col)*256 + dir*128 + u) = hnew;
    u64 pk = pack4(hnew[0], hnew[1], hnew[2], hnew[3]);
    *(u64*)(hb[nxt] + ((u>>3))*256 + (col<<4) + ((hi&1)<<3)) = pk;
    __syncthreads();
  }
}

// =====================================================================
extern "C" void kernel_launch(void* const* d_in, const int* in_sizes, int n_in,
                              void* d_out, int out_size, void* d_ws, size_t ws_size,
                              hipStream_t stream)
{
  (void)in_sizes; (void)n_in; (void)out_size; (void)ws_size;
  const int*   token  = (const int*)  d_in[0];
  const float* emb    = (const float*)d_in[1];
  const float* w_ih1  = (const float*)d_in[2];
  const float* w_hh1  = (const float*)d_in[3];
  const float* b_ih1  = (const float*)d_in[4];
  const float* b_hh1  = (const float*)d_in[5];
  const float* ln_g   = (const float*)d_in[6];
  const float* ln_b   = (const float*)d_in[7];
  const float* w_ih2f = (const float*)d_in[8];
  const float* w_hh2f = (const float*)d_in[9];
  const float* b_ih2f = (const float*)d_in[10];
  const float* b_hh2f = (const float*)d_in[11];
  const float* w_ih2b = (const float*)d_in[12];
  const float* w_hh2b = (const float*)d_in[13];
  const float* b_ih2b = (const float*)d_in[14];
  const float* b_hh2b = (const float*)d_in[15];
  float* out = (float*)d_out;

  char* ws = (char*)d_ws;
  unsigned short* hn    = (unsigned short*)(ws);              //  67,108,864 B
  unsigned short* xg2f  = (unsigned short*)(ws + 67108864);   // 100,663,296 B
  unsigned short* xg2b  = (unsigned short*)(ws + 167772160);  // 100,663,296 B
  // xgV (f32, 393,216 B) aliases the START of the xg2b region: consumed by
  // k_scan1 before k_k3 writes xg2b.
  float*          xgV   = (float*)(ws + 167772160);
  unsigned short* pack1 = (unsigned short*)(ws + 268632064);  //     393,216 B
  unsigned short* pack2 = (unsigned short*)(ws + 269025280);  //     393,216 B
  unsigned short* pack3 = (unsigned short*)(ws + 269418496);  //     196,608 B

  hipLaunchKernelGGL(k_pack,  dim3(240), dim3(256), 0, stream,
                     w_hh1, w_ih2f, w_ih2b, w_hh2f, w_hh2b, pack1, pack2, pack3);
  hipLaunchKernelGGL(k_xgv,   dim3(384), dim3(256), 0, stream,
                     emb, w_ih1, b_ih1, b_hh1, xgV);
  hipLaunchKernelGGL(k_scan1, dim3(8),   dim3(512), 0, stream,
                     token, xgV, pack1, b_hh1, ln_g, ln_b, hn);
  hipLaunchKernelGGL(k_k3,    dim3(512), dim3(512), 0, stream,
                     hn, pack2, xg2f, xg2b);
  hipLaunchKernelGGL(k_scan2, dim3(16),  dim3(512), 0, stream,
                     xg2f, xg2b, pack3, b_ih2f, b_hh2f, b_ih2b, b_hh2b, out);
}